// Round 5
// baseline (31155.359 us; speedup 1.0000x reference)
//
#include <hip/hip_runtime.h>
#include <hip/hip_bf16.h>

// Problem constants (from reference)
#define NA 35
#define NM 18
#define NN 53          // NA+NM
#define TT 48
#define HH 32
// output: h_aqi [1024,35,32] then h_meo [1024,18,32]
#define OUT_MEO_BASE (1024*35*32)

#define GXS 33         // gx/h row stride (33: (33n+c)%32=n+c -> conflict-free)
#define PS  57         // p row stride (57: 25n+j coprime pattern -> conflict-free)

typedef unsigned short u16;

__device__ __forceinline__ float bf(u16 u){ return __uint_as_float(((unsigned)u)<<16); }
__device__ __forceinline__ float dot4(float4 a, float4 b){
  return a.x*b.x + a.y*b.y + a.z*b.z + a.w*b.w;
}

struct Params {
  const void *X_aqi, *X_meo, *ctx, *adj, *adjn;
  const void *emb0,*emb1,*emb2,*emb3,*emb4,*emb5,*emb6,*emb7,*emb8;
  const void *Wxa,*Wxm,*Wua,*Wum;
  const void *a0,*a1,*a2,*a3;   // a_aa, a_am, a_ma, a_mm
  const void *wih_a,*whh_a,*bih_a,*bhh_a,*wih_m,*whh_m,*bih_m,*bhh_m;
  const int *Xae,*Xme;
  void* out;
};

// dtype-agnostic float load: fp32 buffer or bf16 buffer, chosen at runtime.
__device__ __forceinline__ float ldf(const void* p, int i, bool isbf){
  return isbf ? bf(((const u16*)p)[i]) : ((const float*)p)[i];
}

// ~105 KB static LDS -> 1 block/CU, 8 waves (512 thr).
// w kept in ORIGINAL [96][32] layout: ph5 reads it as wave-uniform b128
// broadcasts (bank conflicts irrelevant), 16B-aligned (row stride 128 B).
struct __align__(16) Smem {
  alignas(16) float w[4][96*32];   // wih_a, whh_a, wih_m, whh_m (flat)
  alignas(16) float gb[4][96];     // bih_a, bhh_a, bih_m, bhh_m
  alignas(16) float Wxa[6*32], Wxm[4*32];       // [k][32] attri transforms
  alignas(16) float aAll[4][188];  // a_aa/a_am/a_ma/a_mm, 185 used
  alignas(16) float embA[304];     // 9 embedding tables concatenated (300 used)
  alignas(16) float ctxS[NN][2], ctxD[NN][2];   // context part of src/dst logits
  alignas(16) float uSrc[2][2][14];// (Wu[it] @ a[it*2+v][0:32])   [it][v][k]
  alignas(16) float uDst[2][2][14];// (Wu[it] @ a[v*2+it][92:124]) [it][v][k]
  alignas(16) float biasE[NN*56];  // adj_norm*a[184] (or -1e12 where masked)
  alignas(16) float xin[NN*16];    // per-step raw+embedded inputs, 14 used per node
  alignas(16) float attri[NN*32];  // aggregation values [n][d] (b128 broadcast in ph4)
  alignas(16) float srcv[NN*2], dstv[NN*2];
  alignas(16) float p[NN*PS+7];    // attention exp, stride 57
  alignas(16) float inv[56];       // 1/rowsum (53 used)
  alignas(16) float gx[NN*GXS+3];  // GAT output, stride 33 (per-lane b32)
  alignas(16) float h[NN*GXS+3];   // GRU hidden state, stride 33
};

__global__ __launch_bounds__(512, 2)
void chgat_gru_kernel(Params p){
  __shared__ Smem sm;
  const int tid = threadIdx.x;
  const int b = blockIdx.x;

  // ---------------- stage 0: runtime dtype detection ----------------
  bool isbf = false;
  {
    const unsigned* aw = (const unsigned*)p.adj;
    for (int i=0;i<32;++i){
      unsigned w = aw[i];
      if (w != 0u && w != 0x3F800000u) isbf = true;
    }
  }

  // ---------------- stage 1: stage weights into LDS (flat layout) ----------------
  for (int idx=tid; idx<3072; idx+=512) sm.w[0][idx] = ldf(p.wih_a, idx, isbf);
  for (int idx=tid; idx<3072; idx+=512) sm.w[1][idx] = ldf(p.whh_a, idx, isbf);
  for (int idx=tid; idx<3072; idx+=512) sm.w[2][idx] = ldf(p.wih_m, idx, isbf);
  for (int idx=tid; idx<3072; idx+=512) sm.w[3][idx] = ldf(p.whh_m, idx, isbf);
  if (tid < 96){
    sm.gb[0][tid]=ldf(p.bih_a,tid,isbf); sm.gb[1][tid]=ldf(p.bhh_a,tid,isbf);
    sm.gb[2][tid]=ldf(p.bih_m,tid,isbf); sm.gb[3][tid]=ldf(p.bhh_m,tid,isbf);
  }
  if (tid < 192) sm.Wxa[tid] = ldf(p.Wxa, tid, isbf);
  if (tid < 128) sm.Wxm[tid] = ldf(p.Wxm, tid, isbf);
  if (tid < 185) sm.aAll[0][tid] = ldf(p.a0, tid, isbf);
  if (tid < 185) sm.aAll[1][tid] = ldf(p.a1, tid, isbf);
  if (tid < 185) sm.aAll[2][tid] = ldf(p.a2, tid, isbf);
  if (tid < 185) sm.aAll[3][tid] = ldf(p.a3, tid, isbf);
  // embeddings: offsets {0,70,96,110,158,176,212,238,252}, total 300
  if (tid < 70)  sm.embA[tid]        = ldf(p.emb0, tid, isbf);
  if (tid < 26)  sm.embA[70+tid]     = ldf(p.emb1, tid, isbf);
  if (tid < 14)  sm.embA[96+tid]     = ldf(p.emb2, tid, isbf);
  if (tid < 48)  sm.embA[110+tid]    = ldf(p.emb3, tid, isbf);
  if (tid < 18)  sm.embA[158+tid]    = ldf(p.emb4, tid, isbf);
  if (tid < 36)  sm.embA[176+tid]    = ldf(p.emb5, tid, isbf);
  if (tid < 26)  sm.embA[212+tid]    = ldf(p.emb6, tid, isbf);
  if (tid < 14)  sm.embA[238+tid]    = ldf(p.emb7, tid, isbf);
  if (tid < 48)  sm.embA[252+tid]    = ldf(p.emb8, tid, isbf);
  for (int idx=tid; idx<NN*GXS; idx+=512) sm.h[idx] = 0.f;
  __syncthreads();

  // ---------------- stage 2: batch-invariant attention constants ----------------
  if (tid < 212){
    int i = tid>>2, v = tid&3, it = (i<NA)?0:1;
    float s = 0.f;
    if (v < 2){
      const float* ac = &sm.aAll[it*2+v][32];       // a_sel[32..91] · context
      for (int c=0;c<60;++c) s += ldf(p.ctx, i*60+c, isbf)*ac[c];
      sm.ctxS[i][v] = s;
    } else {
      const float* ac = &sm.aAll[(v-2)*2+it][124];  // a_sel[124..183] · context
      for (int c=0;c<60;++c) s += ldf(p.ctx, i*60+c, isbf)*ac[c];
      sm.ctxD[i][v-2] = s;
    }
  } else if (tid < 324){
    // fold Wu into a: uSrc[it][v] = Wu[it] @ a[it*2+v][0:32]
    //                 uDst[it][v] = Wu[it] @ a[v*2+it][92:124]
    int u = tid - 212;                 // 0..111
    int it = u / 56, rem = u % 56;
    int sd = rem / 28, rem2 = rem % 28;
    int v = rem2 / 14, k = rem2 % 14;
    const void* Wu = it ? p.Wum : p.Wua;
    const float* av = sd ? &sm.aAll[v*2+it][92] : &sm.aAll[it*2+v][0];
    float s = 0.f;
    for (int kk=0;kk<32;++kk) s += ldf(Wu, k*32+kk, isbf)*av[kk];
    if (sd) sm.uDst[it][v][k] = s; else sm.uSrc[it][v][k] = s;
  }
  for (int idx=tid; idx<NN*NN; idx+=512){
    int i = idx/NN, j = idx - i*NN;
    int sel = ((i<NA)?0:2) + ((j<NA)?0:1);
    float ad = ldf(p.adj, idx, isbf);
    sm.biasE[i*56+j] = (ad > 0.f) ? ldf(p.adjn, idx, isbf)*sm.aAll[sel][184] : -1e12f;
  }
  __syncthreads();

  // ---------------- prefetch t=0 inputs (exactly 1 load / thread) ----------------
  // slots: 210 aqi raw | 72 meo raw | 140 aqi idx | 90 meo idx = 512
  float rv = 0.f; int ri = 0;
  {
    int bt = b*TT + 0;
    if (tid < 210)      rv = ldf(p.X_aqi, bt*210 + tid, isbf);
    else if (tid < 282) rv = ldf(p.X_meo, bt*72 + tid - 210, isbf);
    else { int u = tid - 282; ri = (u < 140) ? p.Xae[bt*140 + u] : p.Xme[bt*90 + u - 140]; }
  }

  // ph4/ph5 thread mapping: lane = node, wave owns 4 output dims
  const int lane = tid & 63;
  const int wv   = tid >> 6;        // 0..7
  const int dj0  = wv*4;            // output dims dj0..dj0+3
  const int n5   = (lane < NN) ? lane : NN-1;
  const bool act5 = (lane < NN);
  const bool isA5 = (n5 < NA);
  const float* wih5 = isA5 ? sm.w[0] : sm.w[2];
  const float* whh5 = isA5 ? sm.w[1] : sm.w[3];
  const float* bi5  = isA5 ? sm.gb[0] : sm.gb[2];
  const float* bh5  = isA5 ? sm.gb[1] : sm.gb[3];

  for (int t=0; t<TT; ++t){
    // ---- ph0: consume prefetched inputs into xin ----
    if (tid < 210)      sm.xin[(tid/6)*16 + tid%6] = rv;
    else if (tid < 282){ int q = tid-210; sm.xin[(NA + (q>>2))*16 + (q&3)] = rv; }
    else {
      int u = tid - 282;
      if (u < 140){
        int n = u>>2, e = u&3;
        int off = (e==0)?0:(e==1)?70:(e==2)?96:110;
        sm.xin[n*16 + 6 + 2*e]     = sm.embA[off + ri*2];
        sm.xin[n*16 + 6 + 2*e + 1] = sm.embA[off + ri*2 + 1];
      } else {
        int q = u - 140;
        int n = NA + q/5, e = q%5;
        int off = (e==0)?158:(e==1)?176:(e==2)?212:(e==3)?238:252;
        sm.xin[n*16 + 4 + 2*e]     = sm.embA[off + ri*2];
        sm.xin[n*16 + 4 + 2*e + 1] = sm.embA[off + ri*2 + 1];
      }
    }
    // ---- prefetch t+1 ----
    {
      int tn = (t < TT-1) ? t+1 : t;
      int bt = b*TT + tn;
      if (tid < 210)      rv = ldf(p.X_aqi, bt*210 + tid, isbf);
      else if (tid < 282) rv = ldf(p.X_meo, bt*72 + tid - 210, isbf);
      else { int u = tid - 282; ri = (u < 140) ? p.Xae[bt*140 + u] : p.Xme[bt*90 + u - 140]; }
    }
    __syncthreads();   // (A) xin ready

    // ---- ph1: attri = x@Wx (1696) + src/dst logits via folded Wu (212) ----
    for (int it = tid; it < 1908; it += 512){
      if (it < 1696){
        int n = it>>5, dj = it&31;
        const float* x = &sm.xin[n*16];
        float at = 0.f;
        if (n < NA){
          #pragma unroll
          for (int k=0;k<6;++k) at += x[k]*sm.Wxa[k*32+dj];
        } else {
          #pragma unroll
          for (int k=0;k<4;++k) at += x[k]*sm.Wxm[k*32+dj];
        }
        sm.attri[n*32+dj] = at;
      } else {
        int u = it - 1696;               // 0..211
        int i = u>>2, v = u&3, it2 = (i<NA)?0:1;
        const float* x = &sm.xin[i*16];
        float sacc; const float* uv;
        if (v < 2){ sacc = sm.ctxS[i][v];   uv = sm.uSrc[it2][v]; }
        else      { sacc = sm.ctxD[i][v-2]; uv = sm.uDst[it2][v-2]; }
        #pragma unroll
        for (int k=0;k<14;++k) sacc += x[k]*uv[k];
        if (v < 2) sm.srcv[i*2+v] = sacc; else sm.dstv[i*2+(v-2)] = sacc;
      }
    }
    __syncthreads();   // (B) attri, srcv, dstv ready

    // ---- ph3: e = leaky(src+dst+bias), masked softmax (8 lanes/row) ----
    if (tid < 424){
      int i = tid>>3, l = tid&7, it2 = (i<NA)?0:1;
      float s0 = sm.srcv[i*2+0], s1 = sm.srcv[i*2+1];
      float ev[7];
      float mx = -3.0e38f;
      #pragma unroll
      for (int jj=0; jj<7; ++jj){
        int j = l + jj*8;
        if (j < NN){
          float e = ((j<NA)? s0 : s1) + sm.dstv[j*2+it2] + sm.biasE[i*56+j];
          e = (e >= 0.f) ? e : 0.2f*e;
          ev[jj] = e; mx = fmaxf(mx, e);
        }
      }
      mx = fmaxf(mx, __shfl_xor(mx,1,64));
      mx = fmaxf(mx, __shfl_xor(mx,2,64));
      mx = fmaxf(mx, __shfl_xor(mx,4,64));
      float sum = 0.f;
      #pragma unroll
      for (int jj=0; jj<7; ++jj){
        int j = l + jj*8;
        if (j < NN){
          float pe = __expf(ev[jj] - mx);
          sm.p[i*PS+j] = pe;
          sum += pe;
        }
      }
      sum += __shfl_xor(sum,1,64);
      sum += __shfl_xor(sum,2,64);
      sum += __shfl_xor(sum,4,64);
      if (l == 0) sm.inv[i] = 1.0f/sum;
    }
    __syncthreads();   // (C) p, inv ready

    // ---- ph4: gx[n][dj0..+3] = (p[n]·attri[:,dj]) * inv[n] ----
    // p: per-lane b32 (conflict-free); attri row chunk: wave-uniform b128 broadcast.
    {
      float a0=0.f, a1=0.f, a2=0.f, a3=0.f;
      const float* pr = &sm.p[n5*PS];
      for (int j=0;j<NN;++j){
        float pj = pr[j];
        float4 at = *(const float4*)&sm.attri[j*32 + dj0];
        a0 += pj*at.x; a1 += pj*at.y; a2 += pj*at.z; a3 += pj*at.w;
      }
      float iv = sm.inv[n5];
      if (act5){
        sm.gx[n5*GXS+dj0  ] = a0*iv;
        sm.gx[n5*GXS+dj0+1] = a1*iv;
        sm.gx[n5*GXS+dj0+2] = a2*iv;
        sm.gx[n5*GXS+dj0+3] = a3*iv;
      }
    }
    __syncthreads();   // (D) gx ready

    // ---- ph5: GRU, dims dj0..dj0+3 for node n5. Weights: b128 broadcasts. ----
    {
      float rs0=0,rs1=0,rs2=0,rs3=0, zs0=0,zs1=0,zs2=0,zs3=0;
      float is0=0,is1=0,is2=0,is3=0, hs0=0,hs1=0,hs2=0,hs3=0;
      const float* gxr = &sm.gx[n5*GXS];
      const float* hr  = &sm.h [n5*GXS];
      for (int kc=0; kc<32; kc+=4){
        float4 x4, h4;
        x4.x=gxr[kc]; x4.y=gxr[kc+1]; x4.z=gxr[kc+2]; x4.w=gxr[kc+3];
        h4.x=hr[kc];  h4.y=hr[kc+1];  h4.z=hr[kc+2];  h4.w=hr[kc+3];
        const float* wi = wih5 + kc;
        const float* wh = whh5 + kc;
        #pragma unroll
        for (int q=0;q<4;++q){
          int dj = dj0+q;
          float4 wr = *(const float4*)&wi[(dj    )*32];
          float4 wz = *(const float4*)&wi[(dj+32 )*32];
          float4 wn = *(const float4*)&wi[(dj+64 )*32];
          float4 vr = *(const float4*)&wh[(dj    )*32];
          float4 vz = *(const float4*)&wh[(dj+32 )*32];
          float4 vn = *(const float4*)&wh[(dj+64 )*32];
          float r = dot4(x4,wr) + dot4(h4,vr);
          float z = dot4(x4,wz) + dot4(h4,vz);
          float i_ = dot4(x4,wn);
          float hh = dot4(h4,vn);
          if (q==0){ rs0+=r; zs0+=z; is0+=i_; hs0+=hh; }
          else if (q==1){ rs1+=r; zs1+=z; is1+=i_; hs1+=hh; }
          else if (q==2){ rs2+=r; zs2+=z; is2+=i_; hs2+=hh; }
          else { rs3+=r; zs3+=z; is3+=i_; hs3+=hh; }
        }
      }
      float hold0 = hr[dj0], hold1 = hr[dj0+1], hold2 = hr[dj0+2], hold3 = hr[dj0+3];
      __syncthreads();  // (E) all h reads done before dim-partitioned writes
      if (act5){
        const bool last = (t == TT-1);
        long long ob = isA5 ? ((long long)b*(NA*HH) + (long long)n5*32)
                            : ((long long)OUT_MEO_BASE + (long long)b*(NM*HH) + (long long)(n5-NA)*32);
        #pragma unroll
        for (int q=0;q<4;++q){
          int dj = dj0+q;
          float rsv = (q==0)?rs0:(q==1)?rs1:(q==2)?rs2:rs3;
          float zsv = (q==0)?zs0:(q==1)?zs1:(q==2)?zs2:zs3;
          float isv = (q==0)?is0:(q==1)?is1:(q==2)?is2:is3;
          float hsv = (q==0)?hs0:(q==1)?hs1:(q==2)?hs2:hs3;
          float hov = (q==0)?hold0:(q==1)?hold1:(q==2)?hold2:hold3;
          float r = 1.f/(1.f+__expf(-(rsv + bi5[dj] + bh5[dj])));
          float z = 1.f/(1.f+__expf(-(zsv + bi5[32+dj] + bh5[32+dj])));
          float pre = (isv + bi5[64+dj]) + r*(hsv + bh5[64+dj]);
          float e2 = __expf(2.f*pre);
          float nn2 = 1.f - 2.f/(e2+1.f);          // tanh
          float hnew = (1.f-z)*nn2 + z*hov;
          sm.h[n5*GXS+dj] = hnew;
          if (last){
            if (isbf) ((__hip_bfloat16*)p.out)[ob+dj] = __float2bfloat16(hnew);
            else      ((float*)p.out)[ob+dj] = hnew;
          }
        }
      }
    }
    // loop tail: h writes are ordered before next step's h reads by barrier (A);
    // ph0's xin writes are disjoint from ph5's h region.
  }
}

extern "C" void kernel_launch(void* const* d_in, const int* in_sizes, int n_in,
                              void* d_out, int out_size, void* d_ws, size_t ws_size,
                              hipStream_t stream){
  (void)in_sizes; (void)n_in; (void)d_ws; (void)ws_size; (void)out_size;
  Params p;
  p.X_aqi = d_in[0];
  p.X_meo = d_in[1];
  p.ctx   = d_in[2];
  p.adj   = d_in[3];
  p.adjn  = d_in[4];
  p.emb0 = d_in[5];  p.emb1 = d_in[6];
  p.emb2 = d_in[7];  p.emb3 = d_in[8];
  p.emb4 = d_in[9];  p.emb5 = d_in[10];
  p.emb6 = d_in[11]; p.emb7 = d_in[12];
  p.emb8 = d_in[13];
  p.Wxa = d_in[14]; p.Wxm = d_in[15];
  p.Wua = d_in[16]; p.Wum = d_in[17];
  p.a0 = d_in[18]; p.a1 = d_in[19];
  p.a2 = d_in[20]; p.a3 = d_in[21];
  p.wih_a = d_in[22]; p.whh_a = d_in[23];
  p.bih_a = d_in[24]; p.bhh_a = d_in[25];
  p.wih_m = d_in[26]; p.whh_m = d_in[27];
  p.bih_m = d_in[28]; p.bhh_m = d_in[29];
  p.Xae = (const int*)d_in[30];
  p.Xme = (const int*)d_in[31];
  p.out = d_out;
  hipLaunchKernelGGL(chgat_gru_kernel, dim3(1024), dim3(512), 0, stream, p);
}

// Round 6
// 6461.559 us; speedup vs baseline: 4.8216x; 4.8216x over previous
//
#include <hip/hip_runtime.h>
#include <hip/hip_bf16.h>

#define NA 35
#define NM 18
#define NN 53
#define TT 48
#define HH 32
#define OUT_MEO_BASE (1024*35*32)

typedef unsigned short u16;

__device__ __forceinline__ float bfu(u16 u){ return __uint_as_float(((unsigned)u)<<16); }
__device__ __forceinline__ float flo(unsigned u){ return __uint_as_float(u<<16); }
__device__ __forceinline__ float fhi(unsigned u){ return __uint_as_float(u & 0xFFFF0000u); }
__device__ __forceinline__ u16 cvtbf(float f){
  unsigned u = __float_as_uint(f);
  return (u16)((u + 0x7FFFu + ((u>>16)&1u)) >> 16);   // round-to-nearest-even
}
// dot of float4 with 4 packed bf16 (uint2)
__device__ __forceinline__ float dotw(float4 x, uint2 w){
  return x.x*flo(w.x) + x.y*fhi(w.x) + x.z*flo(w.y) + x.w*fhi(w.y);
}

struct Params {
  const void *X_aqi, *X_meo, *ctx, *adj, *adjn;
  const void *emb0,*emb1,*emb2,*emb3,*emb4,*emb5,*emb6,*emb7,*emb8;
  const void *Wxa,*Wxm,*Wua,*Wum;
  const void *a0,*a1,*a2,*a3;
  const void *wih_a,*whh_a,*bih_a,*bhh_a,*wih_m,*whh_m,*bih_m,*bhh_m;
  const int *Xae,*Xme;
  void* out;
};

__device__ __forceinline__ float ldf(const void* p, int i, bool isbf){
  return isbf ? bfu(((const u16*)p)[i]) : ((const float*)p)[i];
}
__device__ __forceinline__ u16 ldraw(const void* p, int i, bool isbf){
  return isbf ? ((const u16*)p)[i] : cvtbf(((const float*)p)[i]);
}

// ~73.9 KB static LDS -> 2 blocks/CU (8 waves/CU).
struct __align__(16) Smem {
  alignas(16) u16   wbf[4][96*36];   // GRU weights bf16, row stride 36 u16 = 72 B (b64 reads, 2-way free)
  alignas(16) float gb[4][96];       // bih_a, bhh_a, bih_m, bhh_m (fp32)
  alignas(16) float Wxa[6*32], Wxm[4*32];
  alignas(16) float aAll[4][188];
  alignas(16) float embA[304];
  alignas(16) float ctxS[NN][2], ctxD[NN][2];
  alignas(16) float uSrc[2][2][14];
  alignas(16) float uDst[2][2][14];
  alignas(16) u16   biasE[NN*56];    // bf16: adj_norm*a[184] or -1e12
  alignas(16) float xin[NN*16];
  alignas(16) u16   attri_bf[32*60]; // transposed [d][n], bf16, stride 60 (b64 reads, 2-way free)
  alignas(16) float srcv[NN*2], dstv[NN*2];
  alignas(16) float p[NN*56];        // softmax numerators fp32 (b128 broadcast reads; cols 53-55 zeroed)
  alignas(16) float inv[56];
  alignas(16) float gx[NN*32];       // fp32, rows 128 B (b128 broadcast in ph5)
  alignas(16) float h[NN*32];        // fp32 hidden state
};

__global__ __launch_bounds__(256, 2)
void chgat_gru_kernel(Params p){
  __shared__ Smem sm;
  const int tid = threadIdx.x;
  const int b = blockIdx.x;

  // ---------- stage 0: dtype detection (adj is exactly {0,1}) ----------
  bool isbf = false;
  {
    const unsigned* aw = (const unsigned*)p.adj;
    for (int i=0;i<32;++i){
      unsigned w = aw[i];
      if (w != 0u && w != 0x3F800000u) isbf = true;
    }
  }

  // ---------- stage 1: stage constants into LDS ----------
  for (int idx=tid; idx<3072; idx+=256) sm.wbf[0][(idx>>5)*36+(idx&31)] = ldraw(p.wih_a, idx, isbf);
  for (int idx=tid; idx<3072; idx+=256) sm.wbf[1][(idx>>5)*36+(idx&31)] = ldraw(p.whh_a, idx, isbf);
  for (int idx=tid; idx<3072; idx+=256) sm.wbf[2][(idx>>5)*36+(idx&31)] = ldraw(p.wih_m, idx, isbf);
  for (int idx=tid; idx<3072; idx+=256) sm.wbf[3][(idx>>5)*36+(idx&31)] = ldraw(p.whh_m, idx, isbf);
  if (tid < 96){
    sm.gb[0][tid]=ldf(p.bih_a,tid,isbf); sm.gb[1][tid]=ldf(p.bhh_a,tid,isbf);
    sm.gb[2][tid]=ldf(p.bih_m,tid,isbf); sm.gb[3][tid]=ldf(p.bhh_m,tid,isbf);
  }
  if (tid < 192) sm.Wxa[tid] = ldf(p.Wxa, tid, isbf);
  if (tid < 128) sm.Wxm[tid] = ldf(p.Wxm, tid, isbf);
  if (tid < 185){
    sm.aAll[0][tid] = ldf(p.a0, tid, isbf);
    sm.aAll[1][tid] = ldf(p.a1, tid, isbf);
    sm.aAll[2][tid] = ldf(p.a2, tid, isbf);
    sm.aAll[3][tid] = ldf(p.a3, tid, isbf);
  }
  if (tid < 70)  sm.embA[tid]        = ldf(p.emb0, tid, isbf);
  if (tid < 26)  sm.embA[70+tid]     = ldf(p.emb1, tid, isbf);
  if (tid < 14)  sm.embA[96+tid]     = ldf(p.emb2, tid, isbf);
  if (tid < 48)  sm.embA[110+tid]    = ldf(p.emb3, tid, isbf);
  if (tid < 18)  sm.embA[158+tid]    = ldf(p.emb4, tid, isbf);
  if (tid < 36)  sm.embA[176+tid]    = ldf(p.emb5, tid, isbf);
  if (tid < 26)  sm.embA[212+tid]    = ldf(p.emb6, tid, isbf);
  if (tid < 14)  sm.embA[238+tid]    = ldf(p.emb7, tid, isbf);
  if (tid < 48)  sm.embA[252+tid]    = ldf(p.emb8, tid, isbf);
  for (int idx=tid; idx<NN*32; idx+=256) sm.h[idx] = 0.f;
  // zero pads read by b128/b64 tails (cols 53..55 of p, 53..59 of attri_bf)
  if (tid < 159){ int rr=tid/3, cc=53+tid%3; sm.p[rr*56+cc] = 0.f; }
  if (tid < 224){ int rr=tid/7, cc=53+tid%7; sm.attri_bf[rr*60+cc] = 0; }
  __syncthreads();

  // ---------- stage 2: batch-invariant attention constants ----------
  if (tid < 212){
    int i = tid>>2, v = tid&3, it = (i<NA)?0:1;
    float s = 0.f;
    if (v < 2){
      const float* ac = &sm.aAll[it*2+v][32];
      for (int c=0;c<60;++c) s += ldf(p.ctx, i*60+c, isbf)*ac[c];
      sm.ctxS[i][v] = s;
    } else {
      const float* ac = &sm.aAll[(v-2)*2+it][124];
      for (int c=0;c<60;++c) s += ldf(p.ctx, i*60+c, isbf)*ac[c];
      sm.ctxD[i][v-2] = s;
    }
  }
  if (tid < 112){
    // fold Wu into a: uSrc[it][v] = Wu[it] @ a[it*2+v][0:32]; uDst[it][v] = Wu[it] @ a[v*2+it][92:124]
    int u = tid;
    int it = u / 56, rem = u % 56;
    int sd = rem / 28, rem2 = rem % 28;
    int v = rem2 / 14, k = rem2 % 14;
    const void* Wu = it ? p.Wum : p.Wua;
    const float* av = sd ? &sm.aAll[v*2+it][92] : &sm.aAll[it*2+v][0];
    float s = 0.f;
    for (int kk=0;kk<32;++kk) s += ldf(Wu, k*32+kk, isbf)*av[kk];
    if (sd) sm.uDst[it][v][k] = s; else sm.uSrc[it][v][k] = s;
  }
  for (int idx=tid; idx<NN*NN; idx+=256){
    int i = idx/NN, j = idx - i*NN;
    int sel = ((i<NA)?0:2) + ((j<NA)?0:1);
    float ad = ldf(p.adj, idx, isbf);
    sm.biasE[i*56+j] = cvtbf((ad > 0.f) ? ldf(p.adjn, idx, isbf)*sm.aAll[sel][184] : -1e12f);
  }
  __syncthreads();

  // ---------- prefetch t=0 (r3-proven slot scheme: 512 slots over 256 threads) ----------
  float rv1 = 0.f, rv2r = 0.f; int rv2i = 0;
  {
    int bt = b*TT + 0;
    rv1 = (tid < 210) ? ldf(p.X_aqi, bt*210 + tid, isbf) : ldf(p.X_meo, bt*72 + tid - 210, isbf);
    if (tid < 26) rv2r = ldf(p.X_meo, bt*72 + tid + 46, isbf);
    else { int u = tid - 26; rv2i = (u < 140) ? p.Xae[bt*140 + u] : p.Xme[bt*90 + u - 140]; }
  }

  const int ng = tid >> 6;          // wave 0..3
  const int hs = (tid >> 5) & 1;    // half-wave
  const int ks = hs;                // ph5 k-half
  const int d  = tid & 31;          // dim
  const int k0 = ks*16;

  for (int t=0; t<TT; ++t){
    // ---- ph0: scatter prefetched inputs into xin ----
    if (tid < 210) sm.xin[(tid/6)*16 + tid%6] = rv1;
    else { int q = tid-210; sm.xin[(NA + (q>>2))*16 + (q&3)] = rv1; }
    if (tid < 26){ int q = tid + 46; sm.xin[(NA + (q>>2))*16 + (q&3)] = rv2r; }
    else {
      int u = tid - 26;
      if (u < 140){
        int n = u>>2, e = u&3;
        int off = (e==0)?0:(e==1)?70:(e==2)?96:110;
        sm.xin[n*16 + 6 + 2*e]     = sm.embA[off + rv2i*2];
        sm.xin[n*16 + 6 + 2*e + 1] = sm.embA[off + rv2i*2 + 1];
      } else {
        int q = u - 140;
        int n = NA + q/5, e = q%5;
        int off = (e==0)?158:(e==1)?176:(e==2)?212:(e==3)?238:252;
        sm.xin[n*16 + 4 + 2*e]     = sm.embA[off + rv2i*2];
        sm.xin[n*16 + 4 + 2*e + 1] = sm.embA[off + rv2i*2 + 1];
      }
    }
    // prefetch t+1
    {
      int tn = (t < TT-1) ? t+1 : t;
      int bt = b*TT + tn;
      rv1 = (tid < 210) ? ldf(p.X_aqi, bt*210 + tid, isbf) : ldf(p.X_meo, bt*72 + tid - 210, isbf);
      if (tid < 26) rv2r = ldf(p.X_meo, bt*72 + tid + 46, isbf);
      else { int u = tid - 26; rv2i = (u < 140) ? p.Xae[bt*140 + u] : p.Xme[bt*90 + u - 140]; }
    }
    __syncthreads();   // (A) xin ready

    // ---- ph1: attri_t (bf16, transposed) + src/dst logits ----
    for (int it = tid; it < 1908; it += 256){
      if (it < 1696){
        int n = it>>5, dj = it&31;
        const float* x = &sm.xin[n*16];
        float at = 0.f;
        if (n < NA){
          #pragma unroll
          for (int k=0;k<6;++k) at += x[k]*sm.Wxa[k*32+dj];
        } else {
          #pragma unroll
          for (int k=0;k<4;++k) at += x[k]*sm.Wxm[k*32+dj];
        }
        sm.attri_bf[dj*60 + n] = cvtbf(at);
      } else {
        int u = it - 1696;
        int i = u>>2, v = u&3, it2 = (i<NA)?0:1;
        const float* x = &sm.xin[i*16];
        float sacc; const float* uv;
        if (v < 2){ sacc = sm.ctxS[i][v];   uv = sm.uSrc[it2][v]; }
        else      { sacc = sm.ctxD[i][v-2]; uv = sm.uDst[it2][v-2]; }
        #pragma unroll
        for (int k=0;k<14;++k) sacc += x[k]*uv[k];
        if (v < 2) sm.srcv[i*2+v] = sacc; else sm.dstv[i*2+(v-2)] = sacc;
      }
    }
    __syncthreads();   // (B) attri_t, srcv, dstv ready

    // ---- ph3: masked softmax rows (4 lanes/row) ----
    if (tid < 212){
      int i = tid>>2, l = tid&3, it2 = (i<NA)?0:1;
      float s0 = sm.srcv[i*2+0], s1 = sm.srcv[i*2+1];
      float ev[14];
      float mx = -3.0e38f;
      #pragma unroll
      for (int jj=0; jj<14; ++jj){
        int j = l + jj*4;
        if (j < NN){
          float e = ((j<NA)? s0 : s1) + sm.dstv[j*2+it2] + bfu(sm.biasE[i*56+j]);
          e = (e >= 0.f) ? e : 0.2f*e;
          ev[jj] = e; mx = fmaxf(mx, e);
        }
      }
      mx = fmaxf(mx, __shfl_xor(mx,1,64));
      mx = fmaxf(mx, __shfl_xor(mx,2,64));
      float sum = 0.f;
      #pragma unroll
      for (int jj=0; jj<14; ++jj){
        int j = l + jj*4;
        if (j < NN){
          float pe = __expf(ev[jj] - mx);
          sm.p[i*56+j] = pe;
          sum += pe;
        }
      }
      sum += __shfl_xor(sum,1,64);
      sum += __shfl_xor(sum,2,64);
      if (l == 0) sm.inv[i] = 1.0f/sum;
    }
    __syncthreads();   // (C) p, inv ready

    // ---- ph4: gx rows n = ng+4*(2r+hs) (n ≡ ng mod 4 -> same wave as ph5 reader) ----
    {
      const int nb = ng + 4*hs;   // rows nb, nb+8, ..., nb+48
      float c0=0.f,c1=0.f,c2=0.f,c3=0.f,c4=0.f,c5=0.f,c6=0.f;
      #pragma unroll
      for (int jc=0; jc<14; ++jc){
        uint2 ab = *(const uint2*)&sm.attri_bf[d*60 + jc*4];
        float a0=flo(ab.x), a1=fhi(ab.x), a2=flo(ab.y), a3=fhi(ab.y);
        const float* pc = &sm.p[jc*4];
        { float4 q=*(const float4*)&pc[(nb   )*56]; c0 += q.x*a0+q.y*a1+q.z*a2+q.w*a3; }
        { float4 q=*(const float4*)&pc[(nb+ 8)*56]; c1 += q.x*a0+q.y*a1+q.z*a2+q.w*a3; }
        { float4 q=*(const float4*)&pc[(nb+16)*56]; c2 += q.x*a0+q.y*a1+q.z*a2+q.w*a3; }
        { float4 q=*(const float4*)&pc[(nb+24)*56]; c3 += q.x*a0+q.y*a1+q.z*a2+q.w*a3; }
        { float4 q=*(const float4*)&pc[(nb+32)*56]; c4 += q.x*a0+q.y*a1+q.z*a2+q.w*a3; }
        { float4 q=*(const float4*)&pc[(nb+40)*56]; c5 += q.x*a0+q.y*a1+q.z*a2+q.w*a3; }
        if (nb+48 <= 52){ float4 q=*(const float4*)&pc[(nb+48)*56]; c6 += q.x*a0+q.y*a1+q.z*a2+q.w*a3; }
      }
      sm.gx[(nb   )*32+d] = c0*sm.inv[nb];
      sm.gx[(nb+ 8)*32+d] = c1*sm.inv[nb+8];
      sm.gx[(nb+16)*32+d] = c2*sm.inv[nb+16];
      sm.gx[(nb+24)*32+d] = c3*sm.inv[nb+24];
      sm.gx[(nb+32)*32+d] = c4*sm.inv[nb+32];
      if (nb+40 <= 52) sm.gx[(nb+40)*32+d] = c5*sm.inv[nb+40];
      if (nb+48 <= 52) sm.gx[(nb+48)*32+d] = c6*sm.inv[nb+48];
    }
    // no barrier: gx rows ≡ ng (mod 4) written and read by the same wave (DS program order)

    // ---- ph5: GRU; wave ng owns nodes ≡ ng (mod 4); sub-passes of ≤5 nodes ----
    {
      const bool last = (t == TT-1);
      auto gru5 = [&](const u16* __restrict__ wi, const u16* __restrict__ wh,
                      const float* __restrict__ bi, const float* __restrict__ bh,
                      int n0, int mcnt, long long ob0, bool dolast){
        float r0=0.f,r1=0.f,r2=0.f,r3=0.f,r4=0.f;
        float z0=0.f,z1=0.f,z2=0.f,z3=0.f,z4=0.f;
        float i0=0.f,i1=0.f,i2=0.f,i3=0.f,i4=0.f;
        float g0=0.f,g1=0.f,g2=0.f,g3=0.f,g4=0.f;
        #pragma unroll
        for (int kc=0;kc<4;++kc){
          const int kk = k0 + kc*4;
          uint2 wir = *(const uint2*)&wi[( d   )*36+kk];
          uint2 wiz = *(const uint2*)&wi[(32+d)*36+kk];
          uint2 win = *(const uint2*)&wi[(64+d)*36+kk];
          uint2 vhr = *(const uint2*)&wh[( d   )*36+kk];
          uint2 vhz = *(const uint2*)&wh[(32+d)*36+kk];
          uint2 vhn = *(const uint2*)&wh[(64+d)*36+kk];
          {
            float4 x4 = *(const float4*)&sm.gx[(n0   )*32+kk];
            float4 h4 = *(const float4*)&sm.h [(n0   )*32+kk];
            r0 += dotw(x4,wir)+dotw(h4,vhr); z0 += dotw(x4,wiz)+dotw(h4,vhz);
            i0 += dotw(x4,win);              g0 += dotw(h4,vhn);
          }
          if (mcnt>1){
            float4 x4 = *(const float4*)&sm.gx[(n0+ 4)*32+kk];
            float4 h4 = *(const float4*)&sm.h [(n0+ 4)*32+kk];
            r1 += dotw(x4,wir)+dotw(h4,vhr); z1 += dotw(x4,wiz)+dotw(h4,vhz);
            i1 += dotw(x4,win);              g1 += dotw(h4,vhn);
          }
          if (mcnt>2){
            float4 x4 = *(const float4*)&sm.gx[(n0+ 8)*32+kk];
            float4 h4 = *(const float4*)&sm.h [(n0+ 8)*32+kk];
            r2 += dotw(x4,wir)+dotw(h4,vhr); z2 += dotw(x4,wiz)+dotw(h4,vhz);
            i2 += dotw(x4,win);              g2 += dotw(h4,vhn);
          }
          if (mcnt>3){
            float4 x4 = *(const float4*)&sm.gx[(n0+12)*32+kk];
            float4 h4 = *(const float4*)&sm.h [(n0+12)*32+kk];
            r3 += dotw(x4,wir)+dotw(h4,vhr); z3 += dotw(x4,wiz)+dotw(h4,vhz);
            i3 += dotw(x4,win);              g3 += dotw(h4,vhn);
          }
          if (mcnt>4){
            float4 x4 = *(const float4*)&sm.gx[(n0+16)*32+kk];
            float4 h4 = *(const float4*)&sm.h [(n0+16)*32+kk];
            r4 += dotw(x4,wir)+dotw(h4,vhr); z4 += dotw(x4,wiz)+dotw(h4,vhz);
            i4 += dotw(x4,win);              g4 += dotw(h4,vhn);
          }
        }
        // combine k-halves (mcnt is wave-uniform -> guards are wave-uniform)
        r0+=__shfl_xor(r0,32,64); z0+=__shfl_xor(z0,32,64); i0+=__shfl_xor(i0,32,64); g0+=__shfl_xor(g0,32,64);
        if (mcnt>1){ r1+=__shfl_xor(r1,32,64); z1+=__shfl_xor(z1,32,64); i1+=__shfl_xor(i1,32,64); g1+=__shfl_xor(g1,32,64); }
        if (mcnt>2){ r2+=__shfl_xor(r2,32,64); z2+=__shfl_xor(z2,32,64); i2+=__shfl_xor(i2,32,64); g2+=__shfl_xor(g2,32,64); }
        if (mcnt>3){ r3+=__shfl_xor(r3,32,64); z3+=__shfl_xor(z3,32,64); i3+=__shfl_xor(i3,32,64); g3+=__shfl_xor(g3,32,64); }
        if (mcnt>4){ r4+=__shfl_xor(r4,32,64); z4+=__shfl_xor(z4,32,64); i4+=__shfl_xor(i4,32,64); g4+=__shfl_xor(g4,32,64); }
        if (ks == 0){
          float br = bi[d]+bh[d], bz = bi[32+d]+bh[32+d];
          float bin = bi[64+d], bhn = bh[64+d];
          {
            float hold = sm.h[(n0   )*32+d];
            float rr = 1.f/(1.f+__expf(-(r0+br)));
            float zz = 1.f/(1.f+__expf(-(z0+bz)));
            float pre = (i0+bin) + rr*(g0+bhn);
            float e2 = __expf(2.f*pre);
            float hnew = (1.f-zz)*(1.f - 2.f/(e2+1.f)) + zz*hold;
            sm.h[(n0   )*32+d] = hnew;
            if (dolast){ long long oi = ob0 + d;
              if (isbf) ((u16*)p.out)[oi] = cvtbf(hnew); else ((float*)p.out)[oi] = hnew; }
          }
          if (mcnt>1){
            float hold = sm.h[(n0+ 4)*32+d];
            float rr = 1.f/(1.f+__expf(-(r1+br)));
            float zz = 1.f/(1.f+__expf(-(z1+bz)));
            float pre = (i1+bin) + rr*(g1+bhn);
            float e2 = __expf(2.f*pre);
            float hnew = (1.f-zz)*(1.f - 2.f/(e2+1.f)) + zz*hold;
            sm.h[(n0+ 4)*32+d] = hnew;
            if (dolast){ long long oi = ob0 + 128 + d;
              if (isbf) ((u16*)p.out)[oi] = cvtbf(hnew); else ((float*)p.out)[oi] = hnew; }
          }
          if (mcnt>2){
            float hold = sm.h[(n0+ 8)*32+d];
            float rr = 1.f/(1.f+__expf(-(r2+br)));
            float zz = 1.f/(1.f+__expf(-(z2+bz)));
            float pre = (i2+bin) + rr*(g2+bhn);
            float e2 = __expf(2.f*pre);
            float hnew = (1.f-zz)*(1.f - 2.f/(e2+1.f)) + zz*hold;
            sm.h[(n0+ 8)*32+d] = hnew;
            if (dolast){ long long oi = ob0 + 256 + d;
              if (isbf) ((u16*)p.out)[oi] = cvtbf(hnew); else ((float*)p.out)[oi] = hnew; }
          }
          if (mcnt>3){
            float hold = sm.h[(n0+12)*32+d];
            float rr = 1.f/(1.f+__expf(-(r3+br)));
            float zz = 1.f/(1.f+__expf(-(z3+bz)));
            float pre = (i3+bin) + rr*(g3+bhn);
            float e2 = __expf(2.f*pre);
            float hnew = (1.f-zz)*(1.f - 2.f/(e2+1.f)) + zz*hold;
            sm.h[(n0+12)*32+d] = hnew;
            if (dolast){ long long oi = ob0 + 384 + d;
              if (isbf) ((u16*)p.out)[oi] = cvtbf(hnew); else ((float*)p.out)[oi] = hnew; }
          }
          if (mcnt>4){
            float hold = sm.h[(n0+16)*32+d];
            float rr = 1.f/(1.f+__expf(-(r4+br)));
            float zz = 1.f/(1.f+__expf(-(z4+bz)));
            float pre = (i4+bin) + rr*(g4+bhn);
            float e2 = __expf(2.f*pre);
            float hnew = (1.f-zz)*(1.f - 2.f/(e2+1.f)) + zz*hold;
            sm.h[(n0+16)*32+d] = hnew;
            if (dolast){ long long oi = ob0 + 512 + d;
              if (isbf) ((u16*)p.out)[oi] = cvtbf(hnew); else ((float*)p.out)[oi] = hnew; }
          }
        }
      };
      const long long bA = (long long)b*(NA*HH);
      const long long bM = (long long)OUT_MEO_BASE + (long long)b*(NM*HH);
      const int cntA = (ng<3)?9:8;                 // aqi nodes ng+4m, m<cntA
      gru5(sm.wbf[0], sm.wbf[1], sm.gb[0], sm.gb[1], ng,    5,       bA + (long long)ng*32,      last);
      gru5(sm.wbf[0], sm.wbf[1], sm.gb[0], sm.gb[1], ng+20, cntA-5,  bA + (long long)(ng+20)*32, last);
      const int n0m  = NA + ((ng+1)&3);            // meo nodes ≡ ng (mod 4)
      const int cntM = (ng==1 || ng==2) ? 4 : 5;
      gru5(sm.wbf[2], sm.wbf[3], sm.gb[2], sm.gb[3], n0m, cntM, bM + (long long)(n0m-NA)*32, last);
    }
    // loop tail: ph0 writes xin only (disjoint); barrier (A) orders the rest.
  }
}

extern "C" void kernel_launch(void* const* d_in, const int* in_sizes, int n_in,
                              void* d_out, int out_size, void* d_ws, size_t ws_size,
                              hipStream_t stream){
  (void)in_sizes; (void)n_in; (void)d_ws; (void)ws_size; (void)out_size;
  Params p;
  p.X_aqi = d_in[0];
  p.X_meo = d_in[1];
  p.ctx   = d_in[2];
  p.adj   = d_in[3];
  p.adjn  = d_in[4];
  p.emb0 = d_in[5];  p.emb1 = d_in[6];
  p.emb2 = d_in[7];  p.emb3 = d_in[8];
  p.emb4 = d_in[9];  p.emb5 = d_in[10];
  p.emb6 = d_in[11]; p.emb7 = d_in[12];
  p.emb8 = d_in[13];
  p.Wxa = d_in[14]; p.Wxm = d_in[15];
  p.Wua = d_in[16]; p.Wum = d_in[17];
  p.a0 = d_in[18]; p.a1 = d_in[19];
  p.a2 = d_in[20]; p.a3 = d_in[21];
  p.wih_a = d_in[22]; p.whh_a = d_in[23];
  p.bih_a = d_in[24]; p.bhh_a = d_in[25];
  p.wih_m = d_in[26]; p.whh_m = d_in[27];
  p.bih_m = d_in[28]; p.bhh_m = d_in[29];
  p.Xae = (const int*)d_in[30];
  p.Xme = (const int*)d_in[31];
  p.out = d_out;
  hipLaunchKernelGGL(chgat_gru_kernel, dim3(1024), dim3(256), 0, stream, p);
}

// Round 7
// 2903.823 us; speedup vs baseline: 10.7291x; 2.2252x over previous
//
#include <hip/hip_runtime.h>
#include <hip/hip_bf16.h>

#define NA 35
#define NM 18
#define NN 53
#define TT 48
#define HH 32
#define OUT_MEO_BASE (1024*35*32)

typedef unsigned short u16;

__device__ __forceinline__ float bfu(u16 u){ return __uint_as_float(((unsigned)u)<<16); }
__device__ __forceinline__ float flo(unsigned u){ return __uint_as_float(u<<16); }
__device__ __forceinline__ float fhi(unsigned u){ return __uint_as_float(u & 0xFFFF0000u); }
__device__ __forceinline__ u16 cvtbf(float f){
  unsigned u = __float_as_uint(f);
  return (u16)((u + 0x7FFFu + ((u>>16)&1u)) >> 16);   // round-to-nearest-even
}
// dot of float4 with 4 packed bf16 (uint2)
__device__ __forceinline__ float dotw(float4 x, uint2 w){
  return x.x*flo(w.x) + x.y*fhi(w.x) + x.z*flo(w.y) + x.w*fhi(w.y);
}

struct Params {
  const void *X_aqi, *X_meo, *ctx, *adj, *adjn;
  const void *emb0,*emb1,*emb2,*emb3,*emb4,*emb5,*emb6,*emb7,*emb8;
  const void *Wxa,*Wxm,*Wua,*Wum;
  const void *a0,*a1,*a2,*a3;
  const void *wih_a,*whh_a,*bih_a,*bhh_a,*wih_m,*whh_m,*bih_m,*bhh_m;
  const int *Xae,*Xme;
  void* out;
};

__device__ __forceinline__ float ldf(const void* p, int i, bool isbf){
  return isbf ? bfu(((const u16*)p)[i]) : ((const float*)p)[i];
}
__device__ __forceinline__ u16 ldraw(const void* p, int i, bool isbf){
  return isbf ? ((const u16*)p)[i] : cvtbf(((const float*)p)[i]);
}

// ~74 KB static LDS -> 2 blocks/CU (8 waves/CU).
struct __align__(16) Smem {
  alignas(16) u16   wbf[4][96*36];   // GRU weights bf16, row stride 36 u16 = 72 B (b64 reads, 2-way free)
  alignas(16) float gb[4][96];       // bih_a, bhh_a, bih_m, bhh_m (fp32)
  alignas(16) float Wxa[6*32], Wxm[4*32];
  alignas(16) float aAll[4][188];
  alignas(16) float embA[304];
  alignas(16) float ctxS[NN][2], ctxD[NN][2];
  alignas(16) float uSrc[2][2][14];
  alignas(16) float uDst[2][2][14];
  alignas(16) u16   biasE[NN*56];    // bf16: adj_norm*a[184] or -1e12
  alignas(16) float xin[NN*16];
  alignas(16) u16   attri_bf[32*60]; // transposed [d][n], bf16, stride 60 (b64 reads, 2-way free)
  alignas(16) float srcv[NN*2], dstv[NN*2];
  alignas(16) float p[NN*56];        // softmax numerators fp32 (b128 broadcast reads; cols 53-55 zeroed)
  alignas(16) float inv[56];
  alignas(16) float gx[NN*32];       // fp32, rows 128 B (b128 broadcast in ph5)
  alignas(16) float h[NN*32];        // fp32 hidden state
};

// NOTE: __launch_bounds__ min-waves arg REMOVED. Rounds 4/5/6 all show the
// same signature: (.,2) => VGPR hard-capped at 128 => multi-GB scratch
// round-trips through HBM. With no cap the allocator lands <=256 VGPR,
// which still permits 2 waves/SIMD (512-reg pool) = 2 blocks/CU with our
// 74 KB LDS -- the occupancy we wanted, without the spills.
__global__ __launch_bounds__(256)
void chgat_gru_kernel(Params p){
  __shared__ Smem sm;
  const int tid = threadIdx.x;
  const int b = blockIdx.x;

  // ---------- stage 0: dtype detection (adj is exactly {0,1}) ----------
  bool isbf = false;
  {
    const unsigned* aw = (const unsigned*)p.adj;
    for (int i=0;i<32;++i){
      unsigned w = aw[i];
      if (w != 0u && w != 0x3F800000u) isbf = true;
    }
  }

  // ---------- stage 1: stage constants into LDS ----------
  for (int idx=tid; idx<3072; idx+=256) sm.wbf[0][(idx>>5)*36+(idx&31)] = ldraw(p.wih_a, idx, isbf);
  for (int idx=tid; idx<3072; idx+=256) sm.wbf[1][(idx>>5)*36+(idx&31)] = ldraw(p.whh_a, idx, isbf);
  for (int idx=tid; idx<3072; idx+=256) sm.wbf[2][(idx>>5)*36+(idx&31)] = ldraw(p.wih_m, idx, isbf);
  for (int idx=tid; idx<3072; idx+=256) sm.wbf[3][(idx>>5)*36+(idx&31)] = ldraw(p.whh_m, idx, isbf);
  if (tid < 96){
    sm.gb[0][tid]=ldf(p.bih_a,tid,isbf); sm.gb[1][tid]=ldf(p.bhh_a,tid,isbf);
    sm.gb[2][tid]=ldf(p.bih_m,tid,isbf); sm.gb[3][tid]=ldf(p.bhh_m,tid,isbf);
  }
  if (tid < 192) sm.Wxa[tid] = ldf(p.Wxa, tid, isbf);
  if (tid < 128) sm.Wxm[tid] = ldf(p.Wxm, tid, isbf);
  if (tid < 185){
    sm.aAll[0][tid] = ldf(p.a0, tid, isbf);
    sm.aAll[1][tid] = ldf(p.a1, tid, isbf);
    sm.aAll[2][tid] = ldf(p.a2, tid, isbf);
    sm.aAll[3][tid] = ldf(p.a3, tid, isbf);
  }
  if (tid < 70)  sm.embA[tid]        = ldf(p.emb0, tid, isbf);
  if (tid < 26)  sm.embA[70+tid]     = ldf(p.emb1, tid, isbf);
  if (tid < 14)  sm.embA[96+tid]     = ldf(p.emb2, tid, isbf);
  if (tid < 48)  sm.embA[110+tid]    = ldf(p.emb3, tid, isbf);
  if (tid < 18)  sm.embA[158+tid]    = ldf(p.emb4, tid, isbf);
  if (tid < 36)  sm.embA[176+tid]    = ldf(p.emb5, tid, isbf);
  if (tid < 26)  sm.embA[212+tid]    = ldf(p.emb6, tid, isbf);
  if (tid < 14)  sm.embA[238+tid]    = ldf(p.emb7, tid, isbf);
  if (tid < 48)  sm.embA[252+tid]    = ldf(p.emb8, tid, isbf);
  for (int idx=tid; idx<NN*32; idx+=256) sm.h[idx] = 0.f;
  // zero pads read by b128/b64 tails (cols 53..55 of p, 53..59 of attri_bf)
  if (tid < 159){ int rr=tid/3, cc=53+tid%3; sm.p[rr*56+cc] = 0.f; }
  if (tid < 224){ int rr=tid/7, cc=53+tid%7; sm.attri_bf[rr*60+cc] = 0; }
  __syncthreads();

  // ---------- stage 2: batch-invariant attention constants ----------
  if (tid < 212){
    int i = tid>>2, v = tid&3, it = (i<NA)?0:1;
    float s = 0.f;
    if (v < 2){
      const float* ac = &sm.aAll[it*2+v][32];
      for (int c=0;c<60;++c) s += ldf(p.ctx, i*60+c, isbf)*ac[c];
      sm.ctxS[i][v] = s;
    } else {
      const float* ac = &sm.aAll[(v-2)*2+it][124];
      for (int c=0;c<60;++c) s += ldf(p.ctx, i*60+c, isbf)*ac[c];
      sm.ctxD[i][v-2] = s;
    }
  }
  if (tid < 112){
    // fold Wu into a: uSrc[it][v] = Wu[it] @ a[it*2+v][0:32]; uDst[it][v] = Wu[it] @ a[v*2+it][92:124]
    int u = tid;
    int it = u / 56, rem = u % 56;
    int sd = rem / 28, rem2 = rem % 28;
    int v = rem2 / 14, k = rem2 % 14;
    const void* Wu = it ? p.Wum : p.Wua;
    const float* av = sd ? &sm.aAll[v*2+it][92] : &sm.aAll[it*2+v][0];
    float s = 0.f;
    for (int kk=0;kk<32;++kk) s += ldf(Wu, k*32+kk, isbf)*av[kk];
    if (sd) sm.uDst[it][v][k] = s; else sm.uSrc[it][v][k] = s;
  }
  for (int idx=tid; idx<NN*NN; idx+=256){
    int i = idx/NN, j = idx - i*NN;
    int sel = ((i<NA)?0:2) + ((j<NA)?0:1);
    float ad = ldf(p.adj, idx, isbf);
    sm.biasE[i*56+j] = cvtbf((ad > 0.f) ? ldf(p.adjn, idx, isbf)*sm.aAll[sel][184] : -1e12f);
  }
  __syncthreads();

  // ---------- prefetch t=0 (512 slots over 256 threads) ----------
  float rv1 = 0.f, rv2r = 0.f; int rv2i = 0;
  {
    int bt = b*TT + 0;
    rv1 = (tid < 210) ? ldf(p.X_aqi, bt*210 + tid, isbf) : ldf(p.X_meo, bt*72 + tid - 210, isbf);
    if (tid < 26) rv2r = ldf(p.X_meo, bt*72 + tid + 46, isbf);
    else { int u = tid - 26; rv2i = (u < 140) ? p.Xae[bt*140 + u] : p.Xme[bt*90 + u - 140]; }
  }

  const int ng = tid >> 6;          // wave 0..3
  const int hs = (tid >> 5) & 1;    // half-wave
  const int ks = hs;                // ph5 k-half
  const int d  = tid & 31;          // dim
  const int k0 = ks*16;

  for (int t=0; t<TT; ++t){
    // ---- ph0: scatter prefetched inputs into xin ----
    if (tid < 210) sm.xin[(tid/6)*16 + tid%6] = rv1;
    else { int q = tid-210; sm.xin[(NA + (q>>2))*16 + (q&3)] = rv1; }
    if (tid < 26){ int q = tid + 46; sm.xin[(NA + (q>>2))*16 + (q&3)] = rv2r; }
    else {
      int u = tid - 26;
      if (u < 140){
        int n = u>>2, e = u&3;
        int off = (e==0)?0:(e==1)?70:(e==2)?96:110;
        sm.xin[n*16 + 6 + 2*e]     = sm.embA[off + rv2i*2];
        sm.xin[n*16 + 6 + 2*e + 1] = sm.embA[off + rv2i*2 + 1];
      } else {
        int q = u - 140;
        int n = NA + q/5, e = q%5;
        int off = (e==0)?158:(e==1)?176:(e==2)?212:(e==3)?238:252;
        sm.xin[n*16 + 4 + 2*e]     = sm.embA[off + rv2i*2];
        sm.xin[n*16 + 4 + 2*e + 1] = sm.embA[off + rv2i*2 + 1];
      }
    }
    // prefetch t+1
    {
      int tn = (t < TT-1) ? t+1 : t;
      int bt = b*TT + tn;
      rv1 = (tid < 210) ? ldf(p.X_aqi, bt*210 + tid, isbf) : ldf(p.X_meo, bt*72 + tid - 210, isbf);
      if (tid < 26) rv2r = ldf(p.X_meo, bt*72 + tid + 46, isbf);
      else { int u = tid - 26; rv2i = (u < 140) ? p.Xae[bt*140 + u] : p.Xme[bt*90 + u - 140]; }
    }
    __syncthreads();   // (A) xin ready

    // ---- ph1: attri_t (bf16, transposed) + src/dst logits ----
    for (int it = tid; it < 1908; it += 256){
      if (it < 1696){
        int n = it>>5, dj = it&31;
        const float* x = &sm.xin[n*16];
        float at = 0.f;
        if (n < NA){
          #pragma unroll
          for (int k=0;k<6;++k) at += x[k]*sm.Wxa[k*32+dj];
        } else {
          #pragma unroll
          for (int k=0;k<4;++k) at += x[k]*sm.Wxm[k*32+dj];
        }
        sm.attri_bf[dj*60 + n] = cvtbf(at);
      } else {
        int u = it - 1696;
        int i = u>>2, v = u&3, it2 = (i<NA)?0:1;
        const float* x = &sm.xin[i*16];
        float sacc; const float* uv;
        if (v < 2){ sacc = sm.ctxS[i][v];   uv = sm.uSrc[it2][v]; }
        else      { sacc = sm.ctxD[i][v-2]; uv = sm.uDst[it2][v-2]; }
        #pragma unroll
        for (int k=0;k<14;++k) sacc += x[k]*uv[k];
        if (v < 2) sm.srcv[i*2+v] = sacc; else sm.dstv[i*2+(v-2)] = sacc;
      }
    }
    __syncthreads();   // (B) attri_t, srcv, dstv ready

    // ---- ph3: masked softmax rows (4 lanes/row) ----
    if (tid < 212){
      int i = tid>>2, l = tid&3, it2 = (i<NA)?0:1;
      float s0 = sm.srcv[i*2+0], s1 = sm.srcv[i*2+1];
      float ev[14];
      float mx = -3.0e38f;
      #pragma unroll
      for (int jj=0; jj<14; ++jj){
        int j = l + jj*4;
        if (j < NN){
          float e = ((j<NA)? s0 : s1) + sm.dstv[j*2+it2] + bfu(sm.biasE[i*56+j]);
          e = (e >= 0.f) ? e : 0.2f*e;
          ev[jj] = e; mx = fmaxf(mx, e);
        }
      }
      mx = fmaxf(mx, __shfl_xor(mx,1,64));
      mx = fmaxf(mx, __shfl_xor(mx,2,64));
      float sum = 0.f;
      #pragma unroll
      for (int jj=0; jj<14; ++jj){
        int j = l + jj*4;
        if (j < NN){
          float pe = __expf(ev[jj] - mx);
          sm.p[i*56+j] = pe;
          sum += pe;
        }
      }
      sum += __shfl_xor(sum,1,64);
      sum += __shfl_xor(sum,2,64);
      if (l == 0) sm.inv[i] = 1.0f/sum;
    }
    __syncthreads();   // (C) p, inv ready

    // ---- ph4: gx rows n = ng+4*(2r+hs) (n ≡ ng mod 4 -> same wave as ph5 reader) ----
    {
      const int nb = ng + 4*hs;   // rows nb, nb+8, ..., nb+48
      float c0=0.f,c1=0.f,c2=0.f,c3=0.f,c4=0.f,c5=0.f,c6=0.f;
      #pragma unroll
      for (int jc=0; jc<14; ++jc){
        uint2 ab = *(const uint2*)&sm.attri_bf[d*60 + jc*4];
        float a0=flo(ab.x), a1=fhi(ab.x), a2=flo(ab.y), a3=fhi(ab.y);
        const float* pc = &sm.p[jc*4];
        { float4 q=*(const float4*)&pc[(nb   )*56]; c0 += q.x*a0+q.y*a1+q.z*a2+q.w*a3; }
        { float4 q=*(const float4*)&pc[(nb+ 8)*56]; c1 += q.x*a0+q.y*a1+q.z*a2+q.w*a3; }
        { float4 q=*(const float4*)&pc[(nb+16)*56]; c2 += q.x*a0+q.y*a1+q.z*a2+q.w*a3; }
        { float4 q=*(const float4*)&pc[(nb+24)*56]; c3 += q.x*a0+q.y*a1+q.z*a2+q.w*a3; }
        { float4 q=*(const float4*)&pc[(nb+32)*56]; c4 += q.x*a0+q.y*a1+q.z*a2+q.w*a3; }
        { float4 q=*(const float4*)&pc[(nb+40)*56]; c5 += q.x*a0+q.y*a1+q.z*a2+q.w*a3; }
        if (nb+48 <= 52){ float4 q=*(const float4*)&pc[(nb+48)*56]; c6 += q.x*a0+q.y*a1+q.z*a2+q.w*a3; }
      }
      sm.gx[(nb   )*32+d] = c0*sm.inv[nb];
      sm.gx[(nb+ 8)*32+d] = c1*sm.inv[nb+8];
      sm.gx[(nb+16)*32+d] = c2*sm.inv[nb+16];
      sm.gx[(nb+24)*32+d] = c3*sm.inv[nb+24];
      sm.gx[(nb+32)*32+d] = c4*sm.inv[nb+32];
      sm.gx[(nb+40)*32+d] = c5*sm.inv[nb+40];
      if (nb+48 <= 52) sm.gx[(nb+48)*32+d] = c6*sm.inv[nb+48];
    }
    // no barrier: gx rows ≡ ng (mod 4) written and read by the same wave (DS program order)

    // ---- ph5: GRU; wave ng owns nodes ≡ ng (mod 4); sub-passes of ≤5 nodes ----
    {
      const bool last = (t == TT-1);
      auto gru5 = [&](const u16* __restrict__ wi, const u16* __restrict__ wh,
                      const float* __restrict__ bi, const float* __restrict__ bh,
                      int n0, int mcnt, long long ob0, bool dolast){
        float r0=0.f,r1=0.f,r2=0.f,r3=0.f,r4=0.f;
        float z0=0.f,z1=0.f,z2=0.f,z3=0.f,z4=0.f;
        float i0=0.f,i1=0.f,i2=0.f,i3=0.f,i4=0.f;
        float g0=0.f,g1=0.f,g2=0.f,g3=0.f,g4=0.f;
        #pragma unroll
        for (int kc=0;kc<4;++kc){
          const int kk = k0 + kc*4;
          uint2 wir = *(const uint2*)&wi[( d   )*36+kk];
          uint2 wiz = *(const uint2*)&wi[(32+d)*36+kk];
          uint2 win = *(const uint2*)&wi[(64+d)*36+kk];
          uint2 vhr = *(const uint2*)&wh[( d   )*36+kk];
          uint2 vhz = *(const uint2*)&wh[(32+d)*36+kk];
          uint2 vhn = *(const uint2*)&wh[(64+d)*36+kk];
          {
            float4 x4 = *(const float4*)&sm.gx[(n0   )*32+kk];
            float4 h4 = *(const float4*)&sm.h [(n0   )*32+kk];
            r0 += dotw(x4,wir)+dotw(h4,vhr); z0 += dotw(x4,wiz)+dotw(h4,vhz);
            i0 += dotw(x4,win);              g0 += dotw(h4,vhn);
          }
          if (mcnt>1){
            float4 x4 = *(const float4*)&sm.gx[(n0+ 4)*32+kk];
            float4 h4 = *(const float4*)&sm.h [(n0+ 4)*32+kk];
            r1 += dotw(x4,wir)+dotw(h4,vhr); z1 += dotw(x4,wiz)+dotw(h4,vhz);
            i1 += dotw(x4,win);              g1 += dotw(h4,vhn);
          }
          if (mcnt>2){
            float4 x4 = *(const float4*)&sm.gx[(n0+ 8)*32+kk];
            float4 h4 = *(const float4*)&sm.h [(n0+ 8)*32+kk];
            r2 += dotw(x4,wir)+dotw(h4,vhr); z2 += dotw(x4,wiz)+dotw(h4,vhz);
            i2 += dotw(x4,win);              g2 += dotw(h4,vhn);
          }
          if (mcnt>3){
            float4 x4 = *(const float4*)&sm.gx[(n0+12)*32+kk];
            float4 h4 = *(const float4*)&sm.h [(n0+12)*32+kk];
            r3 += dotw(x4,wir)+dotw(h4,vhr); z3 += dotw(x4,wiz)+dotw(h4,vhz);
            i3 += dotw(x4,win);              g3 += dotw(h4,vhn);
          }
          if (mcnt>4){
            float4 x4 = *(const float4*)&sm.gx[(n0+16)*32+kk];
            float4 h4 = *(const float4*)&sm.h [(n0+16)*32+kk];
            r4 += dotw(x4,wir)+dotw(h4,vhr); z4 += dotw(x4,wiz)+dotw(h4,vhz);
            i4 += dotw(x4,win);              g4 += dotw(h4,vhn);
          }
        }
        // combine k-halves (mcnt is wave-uniform -> guards are wave-uniform)
        r0+=__shfl_xor(r0,32,64); z0+=__shfl_xor(z0,32,64); i0+=__shfl_xor(i0,32,64); g0+=__shfl_xor(g0,32,64);
        if (mcnt>1){ r1+=__shfl_xor(r1,32,64); z1+=__shfl_xor(z1,32,64); i1+=__shfl_xor(i1,32,64); g1+=__shfl_xor(g1,32,64); }
        if (mcnt>2){ r2+=__shfl_xor(r2,32,64); z2+=__shfl_xor(z2,32,64); i2+=__shfl_xor(i2,32,64); g2+=__shfl_xor(g2,32,64); }
        if (mcnt>3){ r3+=__shfl_xor(r3,32,64); z3+=__shfl_xor(z3,32,64); i3+=__shfl_xor(i3,32,64); g3+=__shfl_xor(g3,32,64); }
        if (mcnt>4){ r4+=__shfl_xor(r4,32,64); z4+=__shfl_xor(z4,32,64); i4+=__shfl_xor(i4,32,64); g4+=__shfl_xor(g4,32,64); }
        if (ks == 0){
          float br = bi[d]+bh[d], bz = bi[32+d]+bh[32+d];
          float bin = bi[64+d], bhn = bh[64+d];
          {
            float hold = sm.h[(n0   )*32+d];
            float rr = 1.f/(1.f+__expf(-(r0+br)));
            float zz = 1.f/(1.f+__expf(-(z0+bz)));
            float pre = (i0+bin) + rr*(g0+bhn);
            float e2 = __expf(2.f*pre);
            float hnew = (1.f-zz)*(1.f - 2.f/(e2+1.f)) + zz*hold;
            sm.h[(n0   )*32+d] = hnew;
            if (dolast){ long long oi = ob0 + d;
              if (isbf) ((u16*)p.out)[oi] = cvtbf(hnew); else ((float*)p.out)[oi] = hnew; }
          }
          if (mcnt>1){
            float hold = sm.h[(n0+ 4)*32+d];
            float rr = 1.f/(1.f+__expf(-(r1+br)));
            float zz = 1.f/(1.f+__expf(-(z1+bz)));
            float pre = (i1+bin) + rr*(g1+bhn);
            float e2 = __expf(2.f*pre);
            float hnew = (1.f-zz)*(1.f - 2.f/(e2+1.f)) + zz*hold;
            sm.h[(n0+ 4)*32+d] = hnew;
            if (dolast){ long long oi = ob0 + 128 + d;
              if (isbf) ((u16*)p.out)[oi] = cvtbf(hnew); else ((float*)p.out)[oi] = hnew; }
          }
          if (mcnt>2){
            float hold = sm.h[(n0+ 8)*32+d];
            float rr = 1.f/(1.f+__expf(-(r2+br)));
            float zz = 1.f/(1.f+__expf(-(z2+bz)));
            float pre = (i2+bin) + rr*(g2+bhn);
            float e2 = __expf(2.f*pre);
            float hnew = (1.f-zz)*(1.f - 2.f/(e2+1.f)) + zz*hold;
            sm.h[(n0+ 8)*32+d] = hnew;
            if (dolast){ long long oi = ob0 + 256 + d;
              if (isbf) ((u16*)p.out)[oi] = cvtbf(hnew); else ((float*)p.out)[oi] = hnew; }
          }
          if (mcnt>3){
            float hold = sm.h[(n0+12)*32+d];
            float rr = 1.f/(1.f+__expf(-(r3+br)));
            float zz = 1.f/(1.f+__expf(-(z3+bz)));
            float pre = (i3+bin) + rr*(g3+bhn);
            float e2 = __expf(2.f*pre);
            float hnew = (1.f-zz)*(1.f - 2.f/(e2+1.f)) + zz*hold;
            sm.h[(n0+12)*32+d] = hnew;
            if (dolast){ long long oi = ob0 + 384 + d;
              if (isbf) ((u16*)p.out)[oi] = cvtbf(hnew); else ((float*)p.out)[oi] = hnew; }
          }
          if (mcnt>4){
            float hold = sm.h[(n0+16)*32+d];
            float rr = 1.f/(1.f+__expf(-(r4+br)));
            float zz = 1.f/(1.f+__expf(-(z4+bz)));
            float pre = (i4+bin) + rr*(g4+bhn);
            float e2 = __expf(2.f*pre);
            float hnew = (1.f-zz)*(1.f - 2.f/(e2+1.f)) + zz*hold;
            sm.h[(n0+16)*32+d] = hnew;
            if (dolast){ long long oi = ob0 + 512 + d;
              if (isbf) ((u16*)p.out)[oi] = cvtbf(hnew); else ((float*)p.out)[oi] = hnew; }
          }
        }
      };
      const long long bA = (long long)b*(NA*HH);
      const long long bM = (long long)OUT_MEO_BASE + (long long)b*(NM*HH);
      const int cntA = (ng<3)?9:8;                 // aqi nodes ng+4m, m<cntA
      gru5(sm.wbf[0], sm.wbf[1], sm.gb[0], sm.gb[1], ng,    5,       bA + (long long)ng*32,      last);
      gru5(sm.wbf[0], sm.wbf[1], sm.gb[0], sm.gb[1], ng+20, cntA-5,  bA + (long long)(ng+20)*32, last);
      const int n0m  = NA + ((ng+1)&3);            // meo nodes ≡ ng (mod 4)
      const int cntM = (ng==1 || ng==2) ? 4 : 5;
      gru5(sm.wbf[2], sm.wbf[3], sm.gb[2], sm.gb[3], n0m, cntM, bM + (long long)(n0m-NA)*32, last);
    }
    // loop tail: ph0 writes xin only (disjoint); barrier (A) orders the rest.
  }
}

extern "C" void kernel_launch(void* const* d_in, const int* in_sizes, int n_in,
                              void* d_out, int out_size, void* d_ws, size_t ws_size,
                              hipStream_t stream){
  (void)in_sizes; (void)n_in; (void)d_ws; (void)ws_size; (void)out_size;
  Params p;
  p.X_aqi = d_in[0];
  p.X_meo = d_in[1];
  p.ctx   = d_in[2];
  p.adj   = d_in[3];
  p.adjn  = d_in[4];
  p.emb0 = d_in[5];  p.emb1 = d_in[6];
  p.emb2 = d_in[7];  p.emb3 = d_in[8];
  p.emb4 = d_in[9];  p.emb5 = d_in[10];
  p.emb6 = d_in[11]; p.emb7 = d_in[12];
  p.emb8 = d_in[13];
  p.Wxa = d_in[14]; p.Wxm = d_in[15];
  p.Wua = d_in[16]; p.Wum = d_in[17];
  p.a0 = d_in[18]; p.a1 = d_in[19];
  p.a2 = d_in[20]; p.a3 = d_in[21];
  p.wih_a = d_in[22]; p.whh_a = d_in[23];
  p.bih_a = d_in[24]; p.bhh_a = d_in[25];
  p.wih_m = d_in[26]; p.whh_m = d_in[27];
  p.bih_m = d_in[28]; p.bhh_m = d_in[29];
  p.Xae = (const int*)d_in[30];
  p.Xme = (const int*)d_in[31];
  p.out = d_out;
  hipLaunchKernelGGL(chgat_gru_kernel, dim3(1024), dim3(256), 0, stream, p);
}